// Round 1
// baseline (287.183 us; speedup 1.0000x reference)
//
#include <hip/hip_runtime.h>
#include <hip/hip_bf16.h>

typedef __bf16 bf16;
typedef __attribute__((ext_vector_type(8))) __bf16 bf16x8;
typedef __attribute__((ext_vector_type(4))) __bf16 bf16x4;
typedef __attribute__((ext_vector_type(4))) float f32x4;

#define IN_F 512
#define OUT_F 128
#define BM 128
#define BK 64
#define CHUNK 128

// ---- kernel 1: Wt[n][k] = bf16(W[k][n]) ----------------------------------
__global__ __launch_bounds__(256) void wt_convert_kernel(const float* __restrict__ w,
                                                         bf16* __restrict__ wt) {
    int idx = blockIdx.x * 256 + threadIdx.x;   // 0..65535
    int n = idx >> 9;                           // /512
    int k = idx & 511;
    wt[idx] = (bf16)w[k * OUT_F + n];
}

// ---- kernel 2: support[m][n] = bf16( x[m][:] @ W[:][n] ) ------------------
// 128x128 tile, 4 waves (2x2), 16x16x32 bf16 MFMA, reg-staged LDS with
// fused fp32->bf16 conversion, XOR swizzle ((row&7)<<4) on both sides.
__global__ __launch_bounds__(256) void gemm_kernel(const float* __restrict__ x,
                                                   const bf16* __restrict__ wt,
                                                   bf16* __restrict__ support,
                                                   int n_nodes) {
    __shared__ bf16 As[BM * BK];     // [row][k] swizzled, 16 KB
    __shared__ bf16 Bs[OUT_F * BK];  // [n][k]   swizzled, 16 KB

    const int tid  = threadIdx.x;
    const int lane = tid & 63;
    const int wid  = tid >> 6;
    const int wr   = wid >> 1;   // wave row (0..1) -> 64 rows
    const int wc   = wid & 1;    // wave col (0..1) -> 64 cols
    const int row0 = blockIdx.x * BM;

    char* Ab = (char*)As;
    char* Bb = (char*)Bs;

    f32x4 acc[4][4] = {};

    for (int kt = 0; kt < IN_F / BK; ++kt) {
        const int k0 = kt * BK;
        // ---- stage A: 128x64 fp32 -> bf16, 2048 float4s, 8 per thread ----
        #pragma unroll
        for (int i = 0; i < 8; ++i) {
            int li = i * 256 + tid;         // float4 id
            int r  = li >> 4;               // row 0..127
            int c4 = li & 15;               // float4 within row
            int grow = row0 + r;
            float4 v = {0.f, 0.f, 0.f, 0.f};
            if (grow < n_nodes)
                v = *reinterpret_cast<const float4*>(x + (size_t)grow * IN_F + k0 + c4 * 4);
            bf16x4 b;
            b[0] = (bf16)v.x; b[1] = (bf16)v.y; b[2] = (bf16)v.z; b[3] = (bf16)v.w;
            int byte = (r * (BK * 2) + c4 * 8) ^ ((r & 7) << 4);
            *reinterpret_cast<bf16x4*>(Ab + byte) = b;
        }
        // ---- stage B: 128x64 bf16 from Wt, 8B per thread x8 --------------
        #pragma unroll
        for (int i = 0; i < 8; ++i) {
            int li = i * 256 + tid;
            int r  = li >> 4;               // n 0..127
            int c4 = li & 15;
            bf16x4 b = *reinterpret_cast<const bf16x4*>(wt + (size_t)r * IN_F + k0 + c4 * 4);
            int byte = (r * (BK * 2) + c4 * 8) ^ ((r & 7) << 4);
            *reinterpret_cast<bf16x4*>(Bb + byte) = b;
        }
        __syncthreads();

        // ---- MFMA: two K=32 sub-steps ------------------------------------
        #pragma unroll
        for (int kk = 0; kk < 2; ++kk) {
            const int kbyte = kk * 64 + (lane >> 4) * 16;
            bf16x8 a[4], b[4];
            #pragma unroll
            for (int m = 0; m < 4; ++m) {
                int r = wr * 64 + m * 16 + (lane & 15);
                int byte = (r * (BK * 2) + kbyte) ^ ((r & 7) << 4);
                a[m] = *reinterpret_cast<const bf16x8*>(Ab + byte);
            }
            #pragma unroll
            for (int n = 0; n < 4; ++n) {
                int r = wc * 64 + n * 16 + (lane & 15);
                int byte = (r * (BK * 2) + kbyte) ^ ((r & 7) << 4);
                b[n] = *reinterpret_cast<const bf16x8*>(Bb + byte);
            }
            #pragma unroll
            for (int m = 0; m < 4; ++m)
                #pragma unroll
                for (int n = 0; n < 4; ++n)
                    acc[m][n] = __builtin_amdgcn_mfma_f32_16x16x32_bf16(a[m], b[n], acc[m][n], 0, 0, 0);
        }
        __syncthreads();
    }

    // ---- epilogue: C/D layout col=lane&15, row=(lane>>4)*4+j -------------
    #pragma unroll
    for (int m = 0; m < 4; ++m) {
        #pragma unroll
        for (int n = 0; n < 4; ++n) {
            #pragma unroll
            for (int j = 0; j < 4; ++j) {
                int gm = row0 + wr * 64 + m * 16 + (lane >> 4) * 4 + j;
                int gn = wc * 64 + n * 16 + (lane & 15);
                if (gm < n_nodes)
                    support[(size_t)gm * OUT_F + gn] = (bf16)acc[m][n][j];
            }
        }
    }
}

// ---- kernel 3: segment-sum scatter ---------------------------------------
// block = 128 threads (thread t = feature t), CHUNK consecutive (sorted) edges.
// Run-accumulate in registers; interior rows -> plain store, boundary -> atomic.
__global__ __launch_bounds__(128) void scatter_kernel(const int* __restrict__ adj_row,
                                                      const int* __restrict__ adj_col,
                                                      const float* __restrict__ adj_vals,
                                                      const bf16* __restrict__ support,
                                                      float* __restrict__ out,
                                                      int n_edges) {
    __shared__ int   srow[CHUNK];
    __shared__ int   scol[CHUNK];
    __shared__ float sval[CHUNK];

    const int t  = threadIdx.x;
    const int e0 = blockIdx.x * CHUNK;
    const int nE = min(CHUNK, n_edges - e0);

    if (t < nE) {
        srow[t] = adj_row[e0 + t];
        scol[t] = adj_col[e0 + t];
        sval[t] = adj_vals[e0 + t];
    }
    __syncthreads();

    const int firstRow = srow[0];
    const int lastRow  = srow[nE - 1];

    float acc = 0.f;
    int   cur = firstRow;
    for (int i = 0; i < nE; ++i) {
        int r = srow[i];
        if (r != cur) {
            float* dst = out + (size_t)cur * OUT_F + t;
            if (cur == firstRow || cur == lastRow) atomicAdd(dst, acc);
            else                                   *dst = acc;
            acc = 0.f;
            cur = r;
        }
        acc += sval[i] * (float)support[(size_t)scol[i] * OUT_F + t];
    }
    float* dst = out + (size_t)cur * OUT_F + t;
    if (cur == firstRow || cur == lastRow) atomicAdd(dst, acc);
    else                                   *dst = acc;
}

extern "C" void kernel_launch(void* const* d_in, const int* in_sizes, int n_in,
                              void* d_out, int out_size, void* d_ws, size_t ws_size,
                              hipStream_t stream) {
    const float* x        = (const float*)d_in[0];
    const int*   adj_row  = (const int*)d_in[1];
    const int*   adj_col  = (const int*)d_in[2];
    const float* adj_vals = (const float*)d_in[3];
    const float* weight   = (const float*)d_in[4];
    float*       out      = (float*)d_out;

    const int n_nodes = in_sizes[0] / IN_F;      // 100000
    const int n_edges = in_sizes[1];             // 1600000

    bf16* support = (bf16*)d_ws;                                         // 25.6 MB
    bf16* wt      = (bf16*)((char*)d_ws + (size_t)n_nodes * OUT_F * 2);  // 128 KB

    hipMemsetAsync(d_out, 0, (size_t)out_size * sizeof(float), stream);

    wt_convert_kernel<<<(IN_F * OUT_F) / 256, 256, 0, stream>>>(weight, wt);

    int gemm_blocks = (n_nodes + BM - 1) / BM;   // 782
    gemm_kernel<<<gemm_blocks, 256, 0, stream>>>(x, wt, support, n_nodes);

    int scat_blocks = (n_edges + CHUNK - 1) / CHUNK;  // 12500
    scatter_kernel<<<scat_blocks, CHUNK, 0, stream>>>(adj_row, adj_col, adj_vals,
                                                      support, out, n_edges);
}

// Round 2
// 173.290 us; speedup vs baseline: 1.6572x; 1.6572x over previous
//
#include <hip/hip_runtime.h>
#include <hip/hip_bf16.h>

typedef __bf16 bf16;
typedef __attribute__((ext_vector_type(8))) __bf16 bf16x8;
typedef __attribute__((ext_vector_type(4))) __bf16 bf16x4;
typedef __attribute__((ext_vector_type(2))) __bf16 bf16x2;
typedef __attribute__((ext_vector_type(4))) float f32x4;

#define IN_F 512
#define OUT_F 128
#define BM 128
#define BK 64
#define CHUNK 128
#define UNR 16

// ---- kernel 1: Wt[n][k] = bf16(W[k][n]) ----------------------------------
__global__ __launch_bounds__(256) void wt_convert_kernel(const float* __restrict__ w,
                                                         bf16* __restrict__ wt) {
    int idx = blockIdx.x * 256 + threadIdx.x;   // 0..65535
    int n = idx >> 9;                           // /512
    int k = idx & 511;
    wt[idx] = (bf16)w[k * OUT_F + n];
}

// ---- kernel 2: support[m][n] = bf16( x[m][:] @ W[:][n] ) ------------------
// 128x128 tile, 4 waves (2x2), 16x16x32 bf16 MFMA, reg-staged LDS with
// fused fp32->bf16 conversion, XOR swizzle ((row&7)<<4) on both sides.
__global__ __launch_bounds__(256) void gemm_kernel(const float* __restrict__ x,
                                                   const bf16* __restrict__ wt,
                                                   bf16* __restrict__ support,
                                                   int n_nodes) {
    __shared__ bf16 As[BM * BK];     // [row][k] swizzled, 16 KB
    __shared__ bf16 Bs[OUT_F * BK];  // [n][k]   swizzled, 16 KB

    const int tid  = threadIdx.x;
    const int lane = tid & 63;
    const int wid  = tid >> 6;
    const int wr   = wid >> 1;   // wave row (0..1) -> 64 rows
    const int wc   = wid & 1;    // wave col (0..1) -> 64 cols
    const int row0 = blockIdx.x * BM;

    char* Ab = (char*)As;
    char* Bb = (char*)Bs;

    f32x4 acc[4][4] = {};

    for (int kt = 0; kt < IN_F / BK; ++kt) {
        const int k0 = kt * BK;
        // ---- stage A: 128x64 fp32 -> bf16, 2048 float4s, 8 per thread ----
        #pragma unroll
        for (int i = 0; i < 8; ++i) {
            int li = i * 256 + tid;         // float4 id
            int r  = li >> 4;               // row 0..127
            int c4 = li & 15;               // float4 within row
            int grow = row0 + r;
            float4 v = {0.f, 0.f, 0.f, 0.f};
            if (grow < n_nodes)
                v = *reinterpret_cast<const float4*>(x + (size_t)grow * IN_F + k0 + c4 * 4);
            bf16x4 b;
            b[0] = (bf16)v.x; b[1] = (bf16)v.y; b[2] = (bf16)v.z; b[3] = (bf16)v.w;
            int byte = (r * (BK * 2) + c4 * 8) ^ ((r & 7) << 4);
            *reinterpret_cast<bf16x4*>(Ab + byte) = b;
        }
        // ---- stage B: 128x64 bf16 from Wt, 8B per thread x8 --------------
        #pragma unroll
        for (int i = 0; i < 8; ++i) {
            int li = i * 256 + tid;
            int r  = li >> 4;               // n 0..127
            int c4 = li & 15;
            bf16x4 b = *reinterpret_cast<const bf16x4*>(wt + (size_t)r * IN_F + k0 + c4 * 4);
            int byte = (r * (BK * 2) + c4 * 8) ^ ((r & 7) << 4);
            *reinterpret_cast<bf16x4*>(Bb + byte) = b;
        }
        __syncthreads();

        // ---- MFMA: two K=32 sub-steps ------------------------------------
        #pragma unroll
        for (int kk = 0; kk < 2; ++kk) {
            const int kbyte = kk * 64 + (lane >> 4) * 16;
            bf16x8 a[4], b[4];
            #pragma unroll
            for (int m = 0; m < 4; ++m) {
                int r = wr * 64 + m * 16 + (lane & 15);
                int byte = (r * (BK * 2) + kbyte) ^ ((r & 7) << 4);
                a[m] = *reinterpret_cast<const bf16x8*>(Ab + byte);
            }
            #pragma unroll
            for (int n = 0; n < 4; ++n) {
                int r = wc * 64 + n * 16 + (lane & 15);
                int byte = (r * (BK * 2) + kbyte) ^ ((r & 7) << 4);
                b[n] = *reinterpret_cast<const bf16x8*>(Bb + byte);
            }
            #pragma unroll
            for (int m = 0; m < 4; ++m)
                #pragma unroll
                for (int n = 0; n < 4; ++n)
                    acc[m][n] = __builtin_amdgcn_mfma_f32_16x16x32_bf16(a[m], b[n], acc[m][n], 0, 0, 0);
        }
        __syncthreads();
    }

    // ---- epilogue: C/D layout col=lane&15, row=(lane>>4)*4+j -------------
    #pragma unroll
    for (int m = 0; m < 4; ++m) {
        #pragma unroll
        for (int n = 0; n < 4; ++n) {
            #pragma unroll
            for (int j = 0; j < 4; ++j) {
                int gm = row0 + wr * 64 + m * 16 + (lane >> 4) * 4 + j;
                int gn = wc * 64 + n * 16 + (lane & 15);
                if (gm < n_nodes)
                    support[(size_t)gm * OUT_F + gn] = (bf16)acc[m][n][j];
            }
        }
    }
}

// ---- kernel 3: segment-sum scatter ---------------------------------------
// 64 threads/block, thread t owns features [2t, 2t+1]. CHUNK sorted edges per
// block. Two-phase unroll: batch UNR independent gathers (all in flight),
// then serial run-accumulate. Interior rows -> plain store, boundary -> atomic.
__global__ __launch_bounds__(64) void scatter_kernel(const int* __restrict__ adj_row,
                                                     const int* __restrict__ adj_col,
                                                     const float* __restrict__ adj_vals,
                                                     const bf16* __restrict__ support,
                                                     float* __restrict__ out,
                                                     int n_edges) {
    __shared__ int   srow[CHUNK];
    __shared__ int   scol[CHUNK];
    __shared__ float sval[CHUNK];

    const int t  = threadIdx.x;          // 0..63
    const int e0 = blockIdx.x * CHUNK;
    const int nE = min(CHUNK, n_edges - e0);

    // stage metadata; pad tail so the unrolled loop needs no bounds checks
    for (int i = t; i < CHUNK; i += 64) {
        if (i < nE) {
            srow[i] = adj_row[e0 + i];
            scol[i] = adj_col[e0 + i];
            sval[i] = adj_vals[e0 + i];
        } else {
            srow[i] = adj_row[e0 + nE - 1];  // extend last run with zero weight
            scol[i] = 0;
            sval[i] = 0.f;
        }
    }
    __syncthreads();

    const int firstRow = srow[0];
    const int lastRow  = srow[CHUNK - 1];

    float accx = 0.f, accy = 0.f;
    int   cur = firstRow;

    for (int i0 = 0; i0 < CHUNK; i0 += UNR) {
        // phase 1: UNR independent gathers, issued back-to-back
        float mx[UNR], my[UNR];
        #pragma unroll
        for (int u = 0; u < UNR; ++u) {
            int   c = scol[i0 + u];
            float s = sval[i0 + u];
            bf16x2 v = *reinterpret_cast<const bf16x2*>(support + (size_t)c * OUT_F + t * 2);
            mx[u] = s * (float)v[0];
            my[u] = s * (float)v[1];
        }
        // phase 2: serial run-accumulate (block-uniform branches)
        #pragma unroll
        for (int u = 0; u < UNR; ++u) {
            int r = srow[i0 + u];
            if (r != cur) {
                float* dst = out + (size_t)cur * OUT_F + t * 2;
                if (cur == firstRow) {
                    atomicAdd(dst, accx); atomicAdd(dst + 1, accy);
                } else {
                    dst[0] = accx; dst[1] = accy;
                }
                accx = 0.f; accy = 0.f;
                cur = r;
            }
            accx += mx[u]; accy += my[u];
        }
    }
    // final flush: cur == lastRow (padding guarantees it) -> always atomic
    float* dst = out + (size_t)cur * OUT_F + t * 2;
    atomicAdd(dst, accx); atomicAdd(dst + 1, accy);
}

extern "C" void kernel_launch(void* const* d_in, const int* in_sizes, int n_in,
                              void* d_out, int out_size, void* d_ws, size_t ws_size,
                              hipStream_t stream) {
    const float* x        = (const float*)d_in[0];
    const int*   adj_row  = (const int*)d_in[1];
    const int*   adj_col  = (const int*)d_in[2];
    const float* adj_vals = (const float*)d_in[3];
    const float* weight   = (const float*)d_in[4];
    float*       out      = (float*)d_out;

    const int n_nodes = in_sizes[0] / IN_F;      // 100000
    const int n_edges = in_sizes[1];             // 1600000

    bf16* support = (bf16*)d_ws;                                         // 25.6 MB
    bf16* wt      = (bf16*)((char*)d_ws + (size_t)n_nodes * OUT_F * 2);  // 128 KB

    hipMemsetAsync(d_out, 0, (size_t)out_size * sizeof(float), stream);

    wt_convert_kernel<<<(IN_F * OUT_F) / 256, 256, 0, stream>>>(weight, wt);

    int gemm_blocks = (n_nodes + BM - 1) / BM;   // 782
    gemm_kernel<<<gemm_blocks, 256, 0, stream>>>(x, wt, support, n_nodes);

    int scat_blocks = (n_edges + CHUNK - 1) / CHUNK;  // 12500
    scatter_kernel<<<scat_blocks, 64, 0, stream>>>(adj_row, adj_col, adj_vals,
                                                   support, out, n_edges);
}

// Round 3
// 129.715 us; speedup vs baseline: 2.2140x; 1.3359x over previous
//
#include <hip/hip_runtime.h>
#include <hip/hip_bf16.h>

typedef __bf16 bf16;
typedef __attribute__((ext_vector_type(8))) __bf16 bf16x8;
typedef __attribute__((ext_vector_type(4))) __bf16 bf16x4;
typedef __attribute__((ext_vector_type(2))) __bf16 bf16x2;
typedef __attribute__((ext_vector_type(4))) float f32x4;

#define IN_F 512
#define OUT_F 128
#define BM 64
#define BK 64
#define NKT (IN_F / BK)
#define CHUNK 128
#define UNR 16

// ---- kernel 1: Wt[n][k] = bf16(W[k][n]) ----------------------------------
__global__ __launch_bounds__(256) void wt_convert_kernel(const float* __restrict__ w,
                                                         bf16* __restrict__ wt) {
    int idx = blockIdx.x * 256 + threadIdx.x;   // 0..65535
    int n = idx >> 9;                           // /512
    int k = idx & 511;
    wt[idx] = (bf16)w[k * OUT_F + n];
}

// ---- kernel 2: support[m][n] = bf16( x[m][:] @ W[:][n] ) ------------------
// 64x128 tile, 4 waves (each 64 rows x 32 cols), 16x16x32 bf16 MFMA.
// Explicit double-buffered LDS + T14 async-stage: issue next tile's global
// loads BEFORE the MFMA phase (vmcnt wait lands at the dependent ds_write,
// after the MFMAs), one __syncthreads per K-step. XOR swizzle ((r&7)<<4).
__global__ __launch_bounds__(256) void gemm_kernel(const float* __restrict__ x,
                                                   const bf16* __restrict__ wt,
                                                   bf16* __restrict__ support,
                                                   int n_nodes) {
    __shared__ bf16 As[2][BM * BK];     // 2 x 8 KB
    __shared__ bf16 Bs[2][OUT_F * BK];  // 2 x 16 KB

    const int tid  = threadIdx.x;
    const int lane = tid & 63;
    const int wid  = tid >> 6;          // wave owns cols [wid*32, wid*32+32)
    const int row0 = blockIdx.x * BM;

    float4 av[4];   // staged A (fp32)
    bf16x8 bv[4];   // staged B (bf16)

    auto load_tile = [&](int kt) {
        const int k0 = kt * BK;
        #pragma unroll
        for (int i = 0; i < 4; ++i) {           // A: 64 rows x 16 float4
            int li = i * 256 + tid;
            int r = li >> 4, c4 = li & 15;
            int grow = row0 + r;
            float4 v = {0.f, 0.f, 0.f, 0.f};
            if (grow < n_nodes)
                v = *reinterpret_cast<const float4*>(x + (size_t)grow * IN_F + k0 + c4 * 4);
            av[i] = v;
        }
        #pragma unroll
        for (int i = 0; i < 4; ++i) {           // B: 128 rows x 8 bf16x8
            int li = i * 256 + tid;
            int r = li >> 3, c8 = li & 7;
            bv[i] = *reinterpret_cast<const bf16x8*>(wt + (size_t)r * IN_F + k0 + c8 * 8);
        }
    };

    auto write_tile = [&](int buf) {
        char* Ab = (char*)As[buf];
        char* Bb = (char*)Bs[buf];
        #pragma unroll
        for (int i = 0; i < 4; ++i) {
            int li = i * 256 + tid;
            int r = li >> 4, c4 = li & 15;
            bf16x4 b;
            b[0] = (bf16)av[i].x; b[1] = (bf16)av[i].y;
            b[2] = (bf16)av[i].z; b[3] = (bf16)av[i].w;
            *reinterpret_cast<bf16x4*>(Ab + ((r * 128 + c4 * 8) ^ ((r & 7) << 4))) = b;
        }
        #pragma unroll
        for (int i = 0; i < 4; ++i) {
            int li = i * 256 + tid;
            int r = li >> 3, c8 = li & 7;
            *reinterpret_cast<bf16x8*>(Bb + ((r * 128 + c8 * 16) ^ ((r & 7) << 4))) = bv[i];
        }
    };

    f32x4 acc[4][2] = {};

    load_tile(0);
    write_tile(0);
    __syncthreads();

    for (int kt = 0; kt < NKT; ++kt) {
        const int cur = kt & 1;
        if (kt < NKT - 1) load_tile(kt + 1);    // issue early: in flight across MFMA

        const char* Ab = (const char*)As[cur];
        const char* Bb = (const char*)Bs[cur];
        #pragma unroll
        for (int kk = 0; kk < 2; ++kk) {
            const int kbyte = kk * 64 + (lane >> 4) * 16;
            bf16x8 a[4], b[2];
            #pragma unroll
            for (int m = 0; m < 4; ++m) {
                int r = m * 16 + (lane & 15);
                a[m] = *reinterpret_cast<const bf16x8*>(Ab + ((r * 128 + kbyte) ^ ((r & 7) << 4)));
            }
            #pragma unroll
            for (int n = 0; n < 2; ++n) {
                int r = wid * 32 + n * 16 + (lane & 15);
                b[n] = *reinterpret_cast<const bf16x8*>(Bb + ((r * 128 + kbyte) ^ ((r & 7) << 4)));
            }
            #pragma unroll
            for (int m = 0; m < 4; ++m)
                #pragma unroll
                for (int n = 0; n < 2; ++n)
                    acc[m][n] = __builtin_amdgcn_mfma_f32_16x16x32_bf16(a[m], b[n], acc[m][n], 0, 0, 0);
        }

        if (kt < NKT - 1) {
            write_tile(cur ^ 1);                // vmcnt wait lands here
            __syncthreads();
        }
    }

    // ---- epilogue: C/D layout col=lane&15, row=(lane>>4)*4+j -------------
    #pragma unroll
    for (int m = 0; m < 4; ++m) {
        #pragma unroll
        for (int n = 0; n < 2; ++n) {
            #pragma unroll
            for (int j = 0; j < 4; ++j) {
                int gm = row0 + m * 16 + (lane >> 4) * 4 + j;
                int gn = wid * 32 + n * 16 + (lane & 15);
                if (gm < n_nodes)
                    support[(size_t)gm * OUT_F + gn] = (bf16)acc[m][n][j];
            }
        }
    }
}

// ---- kernel 3: segment-sum scatter ---------------------------------------
// 64 threads/block, thread t owns features [2t, 2t+1]. CHUNK sorted edges per
// block. Two-phase unroll: batch UNR independent gathers (all in flight),
// then serial run-accumulate. Interior rows -> plain store, boundary -> atomic.
__global__ __launch_bounds__(64) void scatter_kernel(const int* __restrict__ adj_row,
                                                     const int* __restrict__ adj_col,
                                                     const float* __restrict__ adj_vals,
                                                     const bf16* __restrict__ support,
                                                     float* __restrict__ out,
                                                     int n_edges) {
    __shared__ int   srow[CHUNK];
    __shared__ int   scol[CHUNK];
    __shared__ float sval[CHUNK];

    const int t  = threadIdx.x;          // 0..63
    const int e0 = blockIdx.x * CHUNK;
    const int nE = min(CHUNK, n_edges - e0);

    // stage metadata; pad tail so the unrolled loop needs no bounds checks
    for (int i = t; i < CHUNK; i += 64) {
        if (i < nE) {
            srow[i] = adj_row[e0 + i];
            scol[i] = adj_col[e0 + i];
            sval[i] = adj_vals[e0 + i];
        } else {
            srow[i] = adj_row[e0 + nE - 1];  // extend last run with zero weight
            scol[i] = 0;
            sval[i] = 0.f;
        }
    }
    __syncthreads();

    const int firstRow = srow[0];

    float accx = 0.f, accy = 0.f;
    int   cur = firstRow;

    for (int i0 = 0; i0 < CHUNK; i0 += UNR) {
        // phase 1: UNR independent gathers, issued back-to-back
        float mx[UNR], my[UNR];
        #pragma unroll
        for (int u = 0; u < UNR; ++u) {
            int   c = scol[i0 + u];
            float s = sval[i0 + u];
            bf16x2 v = *reinterpret_cast<const bf16x2*>(support + (size_t)c * OUT_F + t * 2);
            mx[u] = s * (float)v[0];
            my[u] = s * (float)v[1];
        }
        // phase 2: serial run-accumulate (block-uniform branches)
        #pragma unroll
        for (int u = 0; u < UNR; ++u) {
            int r = srow[i0 + u];
            if (r != cur) {
                float* dst = out + (size_t)cur * OUT_F + t * 2;
                if (cur == firstRow) {
                    atomicAdd(dst, accx); atomicAdd(dst + 1, accy);
                } else {
                    dst[0] = accx; dst[1] = accy;
                }
                accx = 0.f; accy = 0.f;
                cur = r;
            }
            accx += mx[u]; accy += my[u];
        }
    }
    // final flush: cur == lastRow (padding guarantees it) -> always atomic
    float* dst = out + (size_t)cur * OUT_F + t * 2;
    atomicAdd(dst, accx); atomicAdd(dst + 1, accy);
}

extern "C" void kernel_launch(void* const* d_in, const int* in_sizes, int n_in,
                              void* d_out, int out_size, void* d_ws, size_t ws_size,
                              hipStream_t stream) {
    const float* x        = (const float*)d_in[0];
    const int*   adj_row  = (const int*)d_in[1];
    const int*   adj_col  = (const int*)d_in[2];
    const float* adj_vals = (const float*)d_in[3];
    const float* weight   = (const float*)d_in[4];
    float*       out      = (float*)d_out;

    const int n_nodes = in_sizes[0] / IN_F;      // 100000
    const int n_edges = in_sizes[1];             // 1600000

    bf16* support = (bf16*)d_ws;                                         // 25.6 MB
    bf16* wt      = (bf16*)((char*)d_ws + (size_t)n_nodes * OUT_F * 2);  // 128 KB

    hipMemsetAsync(d_out, 0, (size_t)out_size * sizeof(float), stream);

    wt_convert_kernel<<<(IN_F * OUT_F) / 256, 256, 0, stream>>>(weight, wt);

    int gemm_blocks = (n_nodes + BM - 1) / BM;   // 1563
    gemm_kernel<<<gemm_blocks, 256, 0, stream>>>(x, wt, support, n_nodes);

    int scat_blocks = (n_edges + CHUNK - 1) / CHUNK;  // 12500
    scatter_kernel<<<scat_blocks, 64, 0, stream>>>(adj_row, adj_col, adj_vals,
                                                   support, out, n_edges);
}

// Round 4
// 126.306 us; speedup vs baseline: 2.2737x; 1.0270x over previous
//
#include <hip/hip_runtime.h>
#include <hip/hip_bf16.h>

typedef __bf16 bf16;
typedef __attribute__((ext_vector_type(8))) __bf16 bf16x8;
typedef __attribute__((ext_vector_type(4))) __bf16 bf16x4;
typedef __attribute__((ext_vector_type(2))) __bf16 bf16x2;
typedef __attribute__((ext_vector_type(4))) float f32x4;

#define IN_F 512
#define OUT_F 128
#define BM 64
#define BK 64
#define NKT (IN_F / BK)
#define CHUNK 128
#define UNR 16

// ---- kernel 1: pack W into MFMA-fragment order ----------------------------
// wt_frag layout: [kt(8)][kk(2)][nb(8)] fragments of 64 lanes x bf16x8.
// Lane l of fragment (kt,kk,nb) holds W rows k = kt*64+kk*32+(l>>4)*8 + e,
// col n = nb*16 + (l&15)  -> a wave's B-fragment load is 1KB contiguous.
__global__ __launch_bounds__(256) void wt_convert_kernel(const float* __restrict__ w,
                                                         bf16* __restrict__ wt_frag) {
    int o = blockIdx.x * 256 + threadIdx.x;     // 0..65535
    int e   = o & 7;
    int l   = (o >> 3) & 63;
    int nb  = (o >> 9) & 7;
    int kkt = o >> 12;                          // kt*2+kk, 0..15
    int n = nb * 16 + (l & 15);
    int k = (kkt >> 1) * 64 + (kkt & 1) * 32 + (l >> 4) * 8 + e;
    wt_frag[o] = (bf16)w[k * OUT_F + n];
}

// ---- kernel 2: support = bf16(x @ W), fused out-zeroing --------------------
// 64x128 tile, 4 waves (each 64 rows x 32 cols), 16x16x32 bf16 MFMA.
// A: reg-staged fp32->bf16 into double-buffered swizzled LDS (16 KB total).
// B: straight from L2-hot fragment-packed wt (no LDS).
// Also zero-stores this block's 64 rows of `out` (drains under the K-loop).
__global__ __launch_bounds__(256) void gemm_kernel(const float* __restrict__ x,
                                                   const bf16* __restrict__ wt_frag,
                                                   bf16* __restrict__ support,
                                                   float* __restrict__ out,
                                                   int n_nodes) {
    __shared__ bf16 As[2][BM * BK];     // 2 x 8 KB

    const int tid  = threadIdx.x;
    const int lane = tid & 63;
    const int wid  = tid >> 6;          // wave owns cols [wid*32, wid*32+32)
    const int row0 = blockIdx.x * BM;

    float4 av[4];   // staged A (fp32)

    auto load_tile = [&](int kt) {
        const int k0 = kt * BK;
        #pragma unroll
        for (int i = 0; i < 4; ++i) {           // A: 64 rows x 16 float4
            int li = i * 256 + tid;
            int r = li >> 4, c4 = li & 15;
            int grow = row0 + r;
            float4 v = {0.f, 0.f, 0.f, 0.f};
            if (grow < n_nodes)
                v = *reinterpret_cast<const float4*>(x + (size_t)grow * IN_F + k0 + c4 * 4);
            av[i] = v;
        }
    };

    auto write_tile = [&](int buf) {
        char* Ab = (char*)As[buf];
        #pragma unroll
        for (int i = 0; i < 4; ++i) {
            int li = i * 256 + tid;
            int r = li >> 4, c4 = li & 15;
            bf16x4 b;
            b[0] = (bf16)av[i].x; b[1] = (bf16)av[i].y;
            b[2] = (bf16)av[i].z; b[3] = (bf16)av[i].w;
            *reinterpret_cast<bf16x4*>(Ab + ((r * 128 + c4 * 8) ^ ((r & 7) << 4))) = b;
        }
    };

    load_tile(0);

    // fused zero-init of this block's output rows (scatter accumulates later)
    {
        float4 z = {0.f, 0.f, 0.f, 0.f};
        const size_t lim = (size_t)n_nodes * OUT_F;
        #pragma unroll
        for (int i = 0; i < 8; ++i) {
            size_t off = (size_t)row0 * OUT_F + (size_t)(i * 256 + tid) * 4;
            if (off < lim)
                *reinterpret_cast<float4*>(out + off) = z;
        }
    }

    write_tile(0);
    __syncthreads();

    f32x4 acc[4][2] = {};

    for (int kt = 0; kt < NKT; ++kt) {
        const int cur = kt & 1;

        // B fragments for this K-step: coalesced 1KB loads from L2-hot wt_frag
        bf16x8 b[2][2];
        #pragma unroll
        for (int kk = 0; kk < 2; ++kk)
            #pragma unroll
            for (int n = 0; n < 2; ++n) {
                int f = (kt * 2 + kk) * 8 + (wid * 2 + n);
                b[kk][n] = *reinterpret_cast<const bf16x8*>(wt_frag + ((size_t)f * 64 + lane) * 8);
            }

        if (kt < NKT - 1) load_tile(kt + 1);    // in flight across MFMA

        const char* Ab = (const char*)As[cur];
        #pragma unroll
        for (int kk = 0; kk < 2; ++kk) {
            const int kbyte = kk * 64 + (lane >> 4) * 16;
            bf16x8 a[4];
            #pragma unroll
            for (int m = 0; m < 4; ++m) {
                int r = m * 16 + (lane & 15);
                a[m] = *reinterpret_cast<const bf16x8*>(Ab + ((r * 128 + kbyte) ^ ((r & 7) << 4)));
            }
            #pragma unroll
            for (int m = 0; m < 4; ++m)
                #pragma unroll
                for (int n = 0; n < 2; ++n)
                    acc[m][n] = __builtin_amdgcn_mfma_f32_16x16x32_bf16(a[m], b[kk][n], acc[m][n], 0, 0, 0);
        }

        if (kt < NKT - 1) {
            write_tile(cur ^ 1);                // vmcnt wait lands here
            __syncthreads();
        }
    }

    // ---- epilogue: C/D layout col=lane&15, row=(lane>>4)*4+j -------------
    #pragma unroll
    for (int m = 0; m < 4; ++m) {
        #pragma unroll
        for (int n = 0; n < 2; ++n) {
            #pragma unroll
            for (int j = 0; j < 4; ++j) {
                int gm = row0 + m * 16 + (lane >> 4) * 4 + j;
                int gn = wid * 32 + n * 16 + (lane & 15);
                if (gm < n_nodes)
                    support[(size_t)gm * OUT_F + gn] = (bf16)acc[m][n][j];
            }
        }
    }
}

// ---- kernel 3: segment-sum scatter ---------------------------------------
// 64 threads/block, thread t owns features [2t, 2t+1]. CHUNK sorted edges per
// block. Two-phase unroll: batch UNR independent gathers (all in flight),
// then serial run-accumulate. Interior rows -> plain store, boundary -> atomic.
__global__ __launch_bounds__(64) void scatter_kernel(const int* __restrict__ adj_row,
                                                     const int* __restrict__ adj_col,
                                                     const float* __restrict__ adj_vals,
                                                     const bf16* __restrict__ support,
                                                     float* __restrict__ out,
                                                     int n_edges) {
    __shared__ int   srow[CHUNK];
    __shared__ int   scol[CHUNK];
    __shared__ float sval[CHUNK];

    const int t  = threadIdx.x;          // 0..63
    const int e0 = blockIdx.x * CHUNK;
    const int nE = min(CHUNK, n_edges - e0);

    // stage metadata; pad tail so the unrolled loop needs no bounds checks
    for (int i = t; i < CHUNK; i += 64) {
        if (i < nE) {
            srow[i] = adj_row[e0 + i];
            scol[i] = adj_col[e0 + i];
            sval[i] = adj_vals[e0 + i];
        } else {
            srow[i] = adj_row[e0 + nE - 1];  // extend last run with zero weight
            scol[i] = 0;
            sval[i] = 0.f;
        }
    }
    __syncthreads();

    const int firstRow = srow[0];

    float accx = 0.f, accy = 0.f;
    int   cur = firstRow;

    for (int i0 = 0; i0 < CHUNK; i0 += UNR) {
        // phase 1: UNR independent gathers, issued back-to-back
        float mx[UNR], my[UNR];
        #pragma unroll
        for (int u = 0; u < UNR; ++u) {
            int   c = scol[i0 + u];
            float s = sval[i0 + u];
            bf16x2 v = *reinterpret_cast<const bf16x2*>(support + (size_t)c * OUT_F + t * 2);
            mx[u] = s * (float)v[0];
            my[u] = s * (float)v[1];
        }
        // phase 2: serial run-accumulate (block-uniform branches)
        #pragma unroll
        for (int u = 0; u < UNR; ++u) {
            int r = srow[i0 + u];
            if (r != cur) {
                float* dst = out + (size_t)cur * OUT_F + t * 2;
                if (cur == firstRow) {
                    atomicAdd(dst, accx); atomicAdd(dst + 1, accy);
                } else {
                    dst[0] = accx; dst[1] = accy;
                }
                accx = 0.f; accy = 0.f;
                cur = r;
            }
            accx += mx[u]; accy += my[u];
        }
    }
    // final flush: cur == lastRow (padding guarantees it) -> always atomic
    float* dst = out + (size_t)cur * OUT_F + t * 2;
    atomicAdd(dst, accx); atomicAdd(dst + 1, accy);
}

extern "C" void kernel_launch(void* const* d_in, const int* in_sizes, int n_in,
                              void* d_out, int out_size, void* d_ws, size_t ws_size,
                              hipStream_t stream) {
    const float* x        = (const float*)d_in[0];
    const int*   adj_row  = (const int*)d_in[1];
    const int*   adj_col  = (const int*)d_in[2];
    const float* adj_vals = (const float*)d_in[3];
    const float* weight   = (const float*)d_in[4];
    float*       out      = (float*)d_out;

    const int n_nodes = in_sizes[0] / IN_F;      // 100000
    const int n_edges = in_sizes[1];             // 1600000

    bf16* support = (bf16*)d_ws;                                         // 25.6 MB
    bf16* wt_frag = (bf16*)((char*)d_ws + (size_t)n_nodes * OUT_F * 2);  // 128 KB

    wt_convert_kernel<<<(IN_F * OUT_F) / 256, 256, 0, stream>>>(weight, wt_frag);

    int gemm_blocks = (n_nodes + BM - 1) / BM;   // 1563
    gemm_kernel<<<gemm_blocks, 256, 0, stream>>>(x, wt_frag, support, out, n_nodes);

    int scat_blocks = (n_edges + CHUNK - 1) / CHUNK;  // 12500
    scatter_kernel<<<scat_blocks, 64, 0, stream>>>(adj_row, adj_col, adj_vals,
                                                   support, out, n_edges);
}